// Round 1
// baseline (1035.766 us; speedup 1.0000x reference)
//
#include <hip/hip_runtime.h>

#define NNODES 65536
#define INC    512
#define NH     4
#define HD     256
#define HDTOT  1024

typedef __bf16 bf16_t;
typedef __bf16 bf16x4_t __attribute__((ext_vector_type(4)));
typedef __bf16 bf16x8_t __attribute__((ext_vector_type(8)));
typedef float  f32x4_t  __attribute__((ext_vector_type(4)));

__device__ __forceinline__ bf16_t f2bf(float f) { return (bf16_t)f; }

// ---------------- K0: W [512][1024] f32 -> Wt [mat][1024][512] bf16 (transposed) ----
__global__ void k0_wt(const float* __restrict__ Wq, const float* __restrict__ Wk,
                      const float* __restrict__ Wv, bf16_t* __restrict__ Wt) {
  __shared__ float tile[32][33];
  int mat = blockIdx.z;
  const float* W = (mat == 0) ? Wq : (mat == 1) ? Wk : Wv;
  int n0 = blockIdx.x * 32, k0 = blockIdx.y * 32;
  int t = threadIdx.x, tc = t & 31, tr = t >> 5;
#pragma unroll
  for (int i = 0; i < 4; ++i)
    tile[tr + i * 8][tc] = W[(size_t)(k0 + tr + i * 8) * HDTOT + n0 + tc];
  __syncthreads();
#pragma unroll
  for (int i = 0; i < 4; ++i)
    Wt[((size_t)mat * HDTOT + n0 + tr + i * 8) * INC + k0 + tc] =
        f2bf(tile[tc][tr + i * 8]);
}

// ---------------- K1: QKV projection + bias + q/k row-L2-normalize ------------------
// grid (12, 512): blockIdx.x = mat*4+head, blockIdx.y = 128-row group. block = 512.
// Writes: qn [N][1024] bf16 ; knT/vT [4][256][N] bf16 (transposed for K2).
__global__ __launch_bounds__(512) void k1_qkv(
    const float* __restrict__ x, const bf16_t* __restrict__ Wt,
    const float* __restrict__ bq, const float* __restrict__ bk,
    const float* __restrict__ bv,
    bf16_t* __restrict__ qn, bf16_t* __restrict__ knT, bf16_t* __restrict__ vT) {
  __shared__ __align__(16) char smem[55296];
  bf16_t* lds_a = (bf16_t*)smem;            // [128][72] bf16 (x tile, pad 8)
  bf16_t* lds_b = (bf16_t*)(smem + 18432);  // [256][72] bf16 (Wt tile)
  bf16_t* ept   = (bf16_t*)smem;            // epilogue tile [64][264|258]

  const int gxy = blockIdx.x;
  const int mat = gxy >> 2, head = gxy & 3;
  const int n0 = blockIdx.y * 128;
  const int t = threadIdx.x;
  const int wid = t >> 6, lane = t & 63;
  const int l15 = lane & 15, l4 = lane >> 4;

  const f32x4_t zero4 = {0.f, 0.f, 0.f, 0.f};
  f32x4_t acc[16];
#pragma unroll
  for (int f = 0; f < 16; ++f) acc[f] = zero4;

  const bf16_t* Wm = Wt + ((size_t)mat * HDTOT + head * HD) * INC;

  for (int kc = 0; kc < INC / 64; ++kc) {
    const int k0 = kc * 64;
    // stage A: x[n0..n0+127][k0..k0+63] f32 -> bf16 LDS
#pragma unroll
    for (int i = 0; i < 4; ++i) {
      int idx = t + i * 512;
      int r = idx >> 4, c4 = (idx & 15) * 4;
      float4 v = *(const float4*)(x + (size_t)(n0 + r) * INC + k0 + c4);
      bf16x4_t b;
      b[0] = f2bf(v.x); b[1] = f2bf(v.y); b[2] = f2bf(v.z); b[3] = f2bf(v.w);
      *(bf16x4_t*)(lds_a + r * 72 + c4) = b;
    }
    // stage B: Wt rows [256][k0..k0+63] bf16 (already k-contiguous)
#pragma unroll
    for (int i = 0; i < 4; ++i) {
      int idx = t + i * 512;
      int r = idx >> 3, c8 = (idx & 7) * 8;
      *(bf16x8_t*)(lds_b + r * 72 + c8) =
          *(const bf16x8_t*)(Wm + (size_t)r * INC + k0 + c8);
    }
    __syncthreads();
#pragma unroll
    for (int ks = 0; ks < 2; ++ks) {
      const int kk = ks * 32 + l4 * 8;
      bf16x8_t af = *(const bf16x8_t*)(lds_a + (wid * 16 + l15) * 72 + kk);
#pragma unroll
      for (int f = 0; f < 16; ++f) {
        bf16x8_t bf_ = *(const bf16x8_t*)(lds_b + (f * 16 + l15) * 72 + kk);
        acc[f] = __builtin_amdgcn_mfma_f32_16x16x32_bf16(af, bf_, acc[f], 0, 0, 0);
      }
    }
    __syncthreads();
  }

  // bias
  const float* bias = (mat == 0) ? bq : (mat == 1) ? bk : bv;
#pragma unroll
  for (int f = 0; f < 16; ++f) {
    float bb = bias[head * HD + f * 16 + l15];
#pragma unroll
    for (int j = 0; j < 4; ++j) acc[f][j] += bb;
  }

  // L2 normalize rows for q (mat 0) and k (mat 1): row fully inside one wave.
  if (mat <= 1) {
    float ssq[4] = {0.f, 0.f, 0.f, 0.f};
#pragma unroll
    for (int f = 0; f < 16; ++f)
#pragma unroll
      for (int j = 0; j < 4; ++j) ssq[j] += acc[f][j] * acc[f][j];
#pragma unroll
    for (int off = 1; off < 16; off <<= 1) {
#pragma unroll
      for (int j = 0; j < 4; ++j) ssq[j] += __shfl_xor(ssq[j], off, 64);
    }
#pragma unroll
    for (int j = 0; j < 4; ++j) {
      float rn = rsqrtf(ssq[j]);
#pragma unroll
      for (int f = 0; f < 16; ++f) acc[f][j] *= rn;
    }
  }

  // write-out in two 64-row halves via LDS (coalesced stores; kn/v transposed)
  const int ldp = (mat == 0) ? 264 : 258;
  for (int ph = 0; ph < 2; ++ph) {
    __syncthreads();
    if ((wid >> 2) == ph) {
      int rloc = (wid & 3) * 16 + l4 * 4;
#pragma unroll
      for (int f = 0; f < 16; ++f)
#pragma unroll
        for (int j = 0; j < 4; ++j)
          ept[(rloc + j) * ldp + f * 16 + l15] = f2bf(acc[f][j]);
    }
    __syncthreads();
    const int hn0 = n0 + ph * 64;
    if (mat == 0) {
#pragma unroll
      for (int i = 0; i < 4; ++i) {
        int idx = t + i * 512;
        int r = idx >> 5, c8 = (idx & 31) * 8;
        *(bf16x8_t*)(qn + (size_t)(hn0 + r) * HDTOT + head * HD + c8) =
            *(const bf16x8_t*)(ept + r * 264 + c8);
      }
    } else {
      int m = t & 255, seg = t >> 8;
      bf16_t* dst = (mat == 1) ? knT : vT;
      unsigned int pack[16];
#pragma unroll
      for (int rr = 0; rr < 32; rr += 2) {
        int r = seg * 32 + rr;
        unsigned int a = *(const unsigned short*)(ept + r * 258 + m);
        unsigned int b = *(const unsigned short*)(ept + (r + 1) * 258 + m);
        pack[rr >> 1] = a | (b << 16);
      }
      uint4* dp = (uint4*)(dst + ((size_t)head * HD + m) * NNODES + hn0 + seg * 32);
#pragma unroll
      for (int i = 0; i < 4; ++i)
        dp[i] = make_uint4(pack[i * 4], pack[i * 4 + 1], pack[i * 4 + 2], pack[i * 4 + 3]);
    }
  }
}

// ---------------- K2: kvT[h][d][m] += (v^T kn) over N chunks; + ksum, vsum ----------
// grid (4, 4 heads, 16 chunks), block 256. Block tile 128x128, wave tile 64x64.
__global__ __launch_bounds__(256) void k2_kv(
    const bf16_t* __restrict__ knT, const bf16_t* __restrict__ vT,
    float* __restrict__ kvT, float* __restrict__ ksum, float* __restrict__ vsum) {
  __shared__ __align__(16) bf16_t la[128 * 72];  // vT rows (d)
  __shared__ __align__(16) bf16_t lb[128 * 72];  // knT rows (m)
  __shared__ float sred[128];

  const int gx = blockIdx.x;
  const int head = blockIdx.y, chunk = blockIdx.z;
  const int td = gx >> 1, tm = gx & 1;
  const int d0 = td * 128, m0 = tm * 128;
  const size_t nbase = (size_t)chunk * 4096;

  const int t = threadIdx.x, wid = t >> 6, lane = t & 63;
  const int l15 = lane & 15, l4 = lane >> 4;
  const int wr = wid >> 1, wc = wid & 1;

  const f32x4_t zero4 = {0.f, 0.f, 0.f, 0.f};
  f32x4_t acc[4][4];
#pragma unroll
  for (int i = 0; i < 4; ++i)
#pragma unroll
    for (int j = 0; j < 4; ++j) acc[i][j] = zero4;

  float psA[4] = {0.f, 0.f, 0.f, 0.f}, psB[4] = {0.f, 0.f, 0.f, 0.f};
  const bf16_t* As = vT + ((size_t)head * HD + d0) * NNODES + nbase;
  const bf16_t* Bs = knT + ((size_t)head * HD + m0) * NNODES + nbase;

  for (int c = 0; c < 64; ++c) {
    const int koff = c * 64;
#pragma unroll
    for (int i = 0; i < 4; ++i) {
      int idx = t + i * 256;
      int r = idx >> 3, c8 = (idx & 7) * 8;
      bf16x8_t av = *(const bf16x8_t*)(As + (size_t)r * NNODES + koff + c8);
      *(bf16x8_t*)(la + r * 72 + c8) = av;
      bf16x8_t bv_ = *(const bf16x8_t*)(Bs + (size_t)r * NNODES + koff + c8);
      *(bf16x8_t*)(lb + r * 72 + c8) = bv_;
      float sa = 0.f, sb = 0.f;
#pragma unroll
      for (int j = 0; j < 8; ++j) { sa += (float)av[j]; sb += (float)bv_[j]; }
      psA[i] += sa; psB[i] += sb;
    }
    __syncthreads();
#pragma unroll
    for (int ks = 0; ks < 2; ++ks) {
      const int kk = ks * 32 + l4 * 8;
      bf16x8_t af[4], bf_[4];
#pragma unroll
      for (int i = 0; i < 4; ++i) {
        af[i]  = *(const bf16x8_t*)(la + (wr * 64 + i * 16 + l15) * 72 + kk);
        bf_[i] = *(const bf16x8_t*)(lb + (wc * 64 + i * 16 + l15) * 72 + kk);
      }
#pragma unroll
      for (int i = 0; i < 4; ++i)
#pragma unroll
        for (int j = 0; j < 4; ++j)
          acc[i][j] = __builtin_amdgcn_mfma_f32_16x16x32_bf16(af[i], bf_[j], acc[i][j], 0, 0, 0);
    }
    __syncthreads();
  }

#pragma unroll
  for (int i = 0; i < 4; ++i)
#pragma unroll
    for (int jj = 0; jj < 4; ++jj)
#pragma unroll
      for (int j = 0; j < 4; ++j) {
        int d = d0 + wr * 64 + i * 16 + l4 * 4 + j;
        int m = m0 + wc * 64 + jj * 16 + l15;
        atomicAdd(&kvT[((size_t)head * HD + d) * HD + m], acc[i][jj][j]);
      }

  if (tm == 0) {  // vsum from A (vT) rows, added exactly once per (head,chunk,d)
    if (t < 128) sred[t] = 0.f;
    __syncthreads();
#pragma unroll
    for (int i = 0; i < 4; ++i) atomicAdd(&sred[(t >> 3) + i * 32], psA[i]);
    __syncthreads();
    if (t < 128) atomicAdd(&vsum[head * HD + d0 + t], sred[t]);
    __syncthreads();
  }
  if (td == 0) {  // ksum from B (knT) rows
    if (t < 128) sred[t] = 0.f;
    __syncthreads();
#pragma unroll
    for (int i = 0; i < 4; ++i) atomicAdd(&sred[(t >> 3) + i * 32], psB[i]);
    __syncthreads();
    if (t < 128) atomicAdd(&ksum[head * HD + m0 + t], sred[t]);
  }
}

// ---------------- K3: kvT f32 -> bf16 -------------------------------------------------
__global__ void k3_cvt(const float* __restrict__ kvT, bf16_t* __restrict__ kvTb) {
  int i = blockIdx.x * 256 + threadIdx.x;
  float4 v = *(const float4*)(kvT + (size_t)i * 4);
  bf16x4_t b;
  b[0] = f2bf(v.x); b[1] = f2bf(v.y); b[2] = f2bf(v.z); b[3] = f2bf(v.w);
  *(bf16x4_t*)(kvTb + (size_t)i * 4) = b;
}

// ---------------- K4: out = mean_h (qn@kv + vsum) / (qn.ksum + N) ---------------------
// grid (1024), block 256. Block tile 64 rows x 256 d, wave tile 16x256.
__global__ __launch_bounds__(256) void k4_out(
    const bf16_t* __restrict__ qn, const bf16_t* __restrict__ kvTb,
    const float* __restrict__ ksum, const float* __restrict__ vsum,
    float* __restrict__ out) {
  __shared__ __align__(16) bf16_t la[64 * 72];    // qn tile [64][64+8]
  __shared__ __align__(16) bf16_t lb[256 * 72];   // kv tile [256 d][64 m +8]
  __shared__ float sdn[256];

  const int n0 = blockIdx.x * 64;
  const int t = threadIdx.x, wid = t >> 6, lane = t & 63;
  const int l15 = lane & 15, l4 = lane >> 4;

  const f32x4_t zero4 = {0.f, 0.f, 0.f, 0.f};
  f32x4_t oacc[16];
#pragma unroll
  for (int f = 0; f < 16; ++f) oacc[f] = zero4;

  for (int h = 0; h < NH; ++h) {
    f32x4_t hacc[16];
#pragma unroll
    for (int f = 0; f < 16; ++f) hacc[f] = zero4;
    float dnp = 0.f;

    for (int mc = 0; mc < 4; ++mc) {
      const int m0 = mc * 64;
#pragma unroll
      for (int i = 0; i < 2; ++i) {
        int idx = t + i * 256;
        int r = idx >> 3, c8 = (idx & 7) * 8;
        *(bf16x8_t*)(la + r * 72 + c8) =
            *(const bf16x8_t*)(qn + (size_t)(n0 + r) * HDTOT + h * HD + m0 + c8);
      }
#pragma unroll
      for (int i = 0; i < 8; ++i) {
        int idx = t + i * 256;
        int r = idx >> 3, c8 = (idx & 7) * 8;
        *(bf16x8_t*)(lb + r * 72 + c8) =
            *(const bf16x8_t*)(kvTb + ((size_t)h * HD + r) * HD + m0 + c8);
      }
      __syncthreads();
      {  // denom partial from staged qn tile
        int r = t & 63, qd = t >> 6;
        float s = 0.f;
#pragma unroll
        for (int j = 0; j < 16; ++j)
          s += (float)la[r * 72 + qd * 16 + j] * ksum[h * HD + m0 + qd * 16 + j];
        dnp += s;
      }
#pragma unroll
      for (int ks = 0; ks < 2; ++ks) {
        const int kk = ks * 32 + l4 * 8;
        bf16x8_t af = *(const bf16x8_t*)(la + (wid * 16 + l15) * 72 + kk);
#pragma unroll
        for (int f = 0; f < 16; ++f) {
          bf16x8_t bf_ = *(const bf16x8_t*)(lb + (f * 16 + l15) * 72 + kk);
          hacc[f] = __builtin_amdgcn_mfma_f32_16x16x32_bf16(af, bf_, hacc[f], 0, 0, 0);
        }
      }
      __syncthreads();
    }
    sdn[t] = dnp;
    __syncthreads();
    if (t < 64) {
      float dn = sdn[t] + sdn[t + 64] + sdn[t + 128] + sdn[t + 192] + 65536.0f;
      sdn[t] = 1.0f / dn;
    }
    __syncthreads();
    float rdn[4];
#pragma unroll
    for (int j = 0; j < 4; ++j) rdn[j] = sdn[wid * 16 + l4 * 4 + j];
#pragma unroll
    for (int f = 0; f < 16; ++f) {
      float vs = vsum[h * HD + f * 16 + l15];
#pragma unroll
      for (int j = 0; j < 4; ++j) oacc[f][j] += (hacc[f][j] + vs) * rdn[j];
    }
    __syncthreads();
  }
#pragma unroll
  for (int f = 0; f < 16; ++f)
#pragma unroll
    for (int j = 0; j < 4; ++j)
      out[(size_t)(n0 + wid * 16 + l4 * 4 + j) * HD + f * 16 + l15] =
          oacc[f][j] * 0.25f;
}

extern "C" void kernel_launch(void* const* d_in, const int* in_sizes, int n_in,
                              void* d_out, int out_size, void* d_ws, size_t ws_size,
                              hipStream_t stream) {
  const float* x  = (const float*)d_in[0];
  const float* Wq = (const float*)d_in[1];
  const float* bq = (const float*)d_in[2];
  const float* Wk = (const float*)d_in[3];
  const float* bk = (const float*)d_in[4];
  const float* Wv = (const float*)d_in[5];
  const float* bv = (const float*)d_in[6];
  float* out = (float*)d_out;
  char* ws = (char*)d_ws;

  // workspace layout (total ~389 MB)
  bf16_t* qn   = (bf16_t*)(ws);                 // [N][1024]        134,217,728 B
  bf16_t* knT  = (bf16_t*)(ws + 134217728L);    // [4][256][N]      134,217,728 B
  bf16_t* vT   = (bf16_t*)(ws + 268435456L);    // [4][256][N]      134,217,728 B
  bf16_t* Wt   = (bf16_t*)(ws + 402653184L);    // [3][1024][512]     3,145,728 B
  float*  kvT  = (float*) (ws + 405798912L);    // [4][256][256]      1,048,576 B
  bf16_t* kvTb = (bf16_t*)(ws + 406847488L);    // [4][256][256]        524,288 B
  float*  ksum = (float*) (ws + 407371776L);    // [4][256]               4,096 B
  float*  vsum = (float*) (ws + 407375872L);    // [4][256]               4,096 B

  hipMemsetAsync(kvT, 0, 1048576, stream);
  hipMemsetAsync(ksum, 0, 8192, stream);  // ksum + vsum contiguous

  k0_wt  <<<dim3(32, 16, 3), 256, 0, stream>>>(Wq, Wk, Wv, Wt);
  k1_qkv <<<dim3(12, 512),   512, 0, stream>>>(x, Wt, bq, bk, bv, qn, knT, vT);
  k2_kv  <<<dim3(4, 4, 16),  256, 0, stream>>>(knT, vT, kvT, ksum, vsum);
  k3_cvt <<<dim3(256),       256, 0, stream>>>(kvT, kvTb);
  k4_out <<<dim3(1024),      256, 0, stream>>>(qn, kvTb, ksum, vsum, out);
}

// Round 2
// 822.777 us; speedup vs baseline: 1.2589x; 1.2589x over previous
//
#include <hip/hip_runtime.h>

#define NNODES 65536
#define INC    512
#define NH     4
#define HD     256
#define HDTOT  1024

typedef __bf16 bf16_t;
typedef __bf16 bf16x4_t __attribute__((ext_vector_type(4)));
typedef __bf16 bf16x8_t __attribute__((ext_vector_type(8)));
typedef float  f32x4_t  __attribute__((ext_vector_type(4)));

__device__ __forceinline__ bf16_t f2bf(float f) { return (bf16_t)f; }

__device__ __forceinline__ void gl_lds16(const void* g, void* l) {
  __builtin_amdgcn_global_load_lds(
      (const __attribute__((address_space(1))) void*)g,
      (__attribute__((address_space(3))) void*)l, 16, 0, 0);
}

// ---------------- K0a: W [512][1024] f32 -> Wt [mat][1024][512] bf16 (transposed) ----
__global__ void k0_wt(const float* __restrict__ Wq, const float* __restrict__ Wk,
                      const float* __restrict__ Wv, bf16_t* __restrict__ Wt) {
  __shared__ float tile[32][33];
  int mat = blockIdx.z;
  const float* W = (mat == 0) ? Wq : (mat == 1) ? Wk : Wv;
  int n0 = blockIdx.x * 32, k0 = blockIdx.y * 32;
  int t = threadIdx.x, tc = t & 31, tr = t >> 5;
#pragma unroll
  for (int i = 0; i < 4; ++i)
    tile[tr + i * 8][tc] = W[(size_t)(k0 + tr + i * 8) * HDTOT + n0 + tc];
  __syncthreads();
#pragma unroll
  for (int i = 0; i < 4; ++i)
    Wt[((size_t)mat * HDTOT + n0 + tr + i * 8) * INC + k0 + tc] =
        f2bf(tile[tc][tr + i * 8]);
}

// ---------------- K0b: x f32 -> xb bf16 ----------------------------------------------
__global__ void k0b_xb(const float* __restrict__ x, bf16_t* __restrict__ xb) {
  size_t i = ((size_t)blockIdx.x * 256 + threadIdx.x) * 8;
  float4 a = *(const float4*)(x + i);
  float4 b = *(const float4*)(x + i + 4);
  bf16x8_t o;
  o[0] = f2bf(a.x); o[1] = f2bf(a.y); o[2] = f2bf(a.z); o[3] = f2bf(a.w);
  o[4] = f2bf(b.x); o[5] = f2bf(b.y); o[6] = f2bf(b.z); o[7] = f2bf(b.w);
  *(bf16x8_t*)(xb + i) = o;
}

// ---------------- K1: QKV projection (m97-style gl_lds GEMM) + bias + norm ----------
// grid (12, 512): blockIdx.x = mat*4+head (N-tile 256 = one (mat,head)),
// blockIdx.y = 128-row chunk. 512 threads = 8 waves (2 M x 4 N), wave tile 64x64.
__global__ __launch_bounds__(512, 4) void k1_qkv(
    const bf16_t* __restrict__ xb, const bf16_t* __restrict__ Wt,
    const float* __restrict__ bq, const float* __restrict__ bk,
    const float* __restrict__ bv,
    bf16_t* __restrict__ qn, bf16_t* __restrict__ knT, bf16_t* __restrict__ vT,
    float* __restrict__ ksum, float* __restrict__ vsum) {
  __shared__ __align__(16) char smem[52224];
  char* la = smem;                         // A tile [128][128B] (bf16 [128][64])
  char* lb = smem + 16384;                 // B tile [256][128B]
  bf16_t* ept = (bf16_t*)smem;             // epilogue tile [64][264|258]
  float* sred  = (float*)(smem + 49152);   // [128][4] row-ssq partials
  float* sredc = (float*)(smem + 51200);   // [256] col-sum partials

  const int gxy = blockIdx.x;
  const int mat = gxy >> 2, head = gxy & 3;
  const int n0 = blockIdx.y * 128;
  const int t = threadIdx.x;
  const int wid = t >> 6, lane = t & 63;
  const int l15 = lane & 15, l4 = lane >> 4;
  const int wr = wid >> 2, wc = wid & 3;

  const f32x4_t zero4 = {0.f, 0.f, 0.f, 0.f};
  f32x4_t acc[4][4];
#pragma unroll
  for (int i = 0; i < 4; ++i)
#pragma unroll
    for (int j = 0; j < 4; ++j) acc[i][j] = zero4;

  const char* Ab = (const char*)(xb + (size_t)n0 * INC);                       // 1024B rows
  const char* Bb = (const char*)(Wt + ((size_t)mat * HDTOT + head * HD) * INC);

  for (int kc = 0; kc < 8; ++kc) {
    const int kb = kc * 128;  // k byte offset
#pragma unroll
    for (int i = 0; i < 2; ++i) {  // A: 16KB = 2 issues x 512thr x 16B
      int ow = i * 8192 + wid * 1024;
      int o = ow + lane * 16;
      gl_lds16(Ab + (size_t)(o >> 7) * 1024 + kb + (o & 127), la + ow);
    }
#pragma unroll
    for (int i = 0; i < 4; ++i) {  // B: 32KB = 4 issues
      int ow = i * 8192 + wid * 1024;
      int o = ow + lane * 16;
      gl_lds16(Bb + (size_t)(o >> 7) * 1024 + kb + (o & 127), lb + ow);
    }
    __syncthreads();
#pragma unroll
    for (int ks = 0; ks < 2; ++ks) {
      const int cc = ks * 64 + l4 * 16;  // col byte offset
      bf16x8_t af[4], bfr[4];
#pragma unroll
      for (int i = 0; i < 4; ++i)
        af[i] = *(const bf16x8_t*)(la + (wr * 64 + i * 16 + l15) * 128 + cc);
#pragma unroll
      for (int j = 0; j < 4; ++j)
        bfr[j] = *(const bf16x8_t*)(lb + (wc * 64 + j * 16 + l15) * 128 + cc);
#pragma unroll
      for (int i = 0; i < 4; ++i)
#pragma unroll
        for (int j = 0; j < 4; ++j)
          acc[i][j] = __builtin_amdgcn_mfma_f32_16x16x32_bf16(af[i], bfr[j], acc[i][j], 0, 0, 0);
    }
    __syncthreads();
  }

  // bias: col = wc*64 + jf*16 + l15
  const float* bias = (mat == 0) ? bq : (mat == 1) ? bk : bv;
#pragma unroll
  for (int jf = 0; jf < 4; ++jf) {
    float bb = bias[head * HD + wc * 64 + jf * 16 + l15];
#pragma unroll
    for (int i = 0; i < 4; ++i)
#pragma unroll
      for (int jj = 0; jj < 4; ++jj) acc[i][jf][jj] += bb;
  }

  // L2 row-normalize (q, k). Rows span 4 waves (wc) -> LDS reduce.
  if (mat <= 1) {
    float ss[4][4];
#pragma unroll
    for (int i = 0; i < 4; ++i)
#pragma unroll
      for (int jj = 0; jj < 4; ++jj) {
        float s = 0.f;
#pragma unroll
        for (int jf = 0; jf < 4; ++jf) s += acc[i][jf][jj] * acc[i][jf][jj];
        ss[i][jj] = s;
      }
#pragma unroll
    for (int off = 1; off < 16; off <<= 1)
#pragma unroll
      for (int i = 0; i < 4; ++i)
#pragma unroll
        for (int jj = 0; jj < 4; ++jj) ss[i][jj] += __shfl_xor(ss[i][jj], off, 64);
    if (l15 == 0) {
#pragma unroll
      for (int i = 0; i < 4; ++i)
#pragma unroll
        for (int jj = 0; jj < 4; ++jj)
          sred[(wr * 64 + i * 16 + l4 * 4 + jj) * 4 + wc] = ss[i][jj];
    }
    __syncthreads();
#pragma unroll
    for (int i = 0; i < 4; ++i)
#pragma unroll
      for (int jj = 0; jj < 4; ++jj) {
        int row = wr * 64 + i * 16 + l4 * 4 + jj;
        float s = sred[row * 4] + sred[row * 4 + 1] + sred[row * 4 + 2] + sred[row * 4 + 3];
        float rn = rsqrtf(s);
#pragma unroll
        for (int jf = 0; jf < 4; ++jf) acc[i][jf][jj] *= rn;
      }
  }

  // column sums (ksum from normalized k, vsum from v) via LDS + 1 global atomic/col
  if (mat >= 1) {
    float cs[4];
#pragma unroll
    for (int jf = 0; jf < 4; ++jf) {
      float s = 0.f;
#pragma unroll
      for (int i = 0; i < 4; ++i)
#pragma unroll
        for (int jj = 0; jj < 4; ++jj) s += acc[i][jf][jj];
      s += __shfl_xor(s, 16, 64);
      s += __shfl_xor(s, 32, 64);
      cs[jf] = s;
    }
    if (t < 256) sredc[t] = 0.f;
    __syncthreads();
    if (l4 == 0) {
#pragma unroll
      for (int jf = 0; jf < 4; ++jf)
        atomicAdd(&sredc[wc * 64 + jf * 16 + l15], cs[jf]);
    }
    __syncthreads();
    float* dstSum = (mat == 1) ? ksum : vsum;
    if (t < 256) atomicAdd(dstSum + head * HD + t, sredc[t]);
  }

  // write-out in two 64-row halves via LDS (coalesced; kn/v transposed)
  const int ldp = (mat == 0) ? 264 : 258;
  for (int ph = 0; ph < 2; ++ph) {
    __syncthreads();
    if (wr == ph) {
#pragma unroll
      for (int i = 0; i < 4; ++i)
#pragma unroll
        for (int jf = 0; jf < 4; ++jf)
#pragma unroll
          for (int jj = 0; jj < 4; ++jj)
            ept[(i * 16 + l4 * 4 + jj) * ldp + wc * 64 + jf * 16 + l15] =
                f2bf(acc[i][jf][jj]);
    }
    __syncthreads();
    const int hn0 = n0 + ph * 64;
    if (mat == 0) {
#pragma unroll
      for (int i = 0; i < 4; ++i) {
        int idx = t + i * 512;
        int r = idx >> 5, c8 = (idx & 31) * 8;
        *(bf16x8_t*)(qn + (size_t)(hn0 + r) * HDTOT + head * HD + c8) =
            *(const bf16x8_t*)(ept + r * 264 + c8);
      }
    } else {
      int m = t & 255, seg = t >> 8;
      bf16_t* dst = (mat == 1) ? knT : vT;
      unsigned int pack[16];
#pragma unroll
      for (int rr = 0; rr < 32; rr += 2) {
        int r = seg * 32 + rr;
        unsigned int a = *(const unsigned short*)(ept + r * 258 + m);
        unsigned int b = *(const unsigned short*)(ept + (r + 1) * 258 + m);
        pack[rr >> 1] = a | (b << 16);
      }
      uint4* dp = (uint4*)(dst + ((size_t)head * HD + m) * NNODES + hn0 + seg * 32);
#pragma unroll
      for (int i = 0; i < 4; ++i)
        dp[i] = make_uint4(pack[i * 4], pack[i * 4 + 1], pack[i * 4 + 2], pack[i * 4 + 3]);
    }
  }
}

// ---------------- K2: kvT[h][d][m] += (v^T kn) over N chunks (pure GEMM) ------------
// grid (4, 4 heads, 16 chunks), block 256 = 4 waves (2x2), block tile 128x128.
__global__ __launch_bounds__(256, 4) void k2_kv(
    const bf16_t* __restrict__ knT, const bf16_t* __restrict__ vT,
    float* __restrict__ kvT) {
  __shared__ __align__(16) char smem[32768];
  char* la = smem;           // vT rows (d) [128][128B]
  char* lb = smem + 16384;   // knT rows (m)

  const int gx = blockIdx.x;
  const int head = blockIdx.y, chunk = blockIdx.z;
  const int td = gx >> 1, tm = gx & 1;
  const int d0 = td * 128, m0 = tm * 128;

  const int t = threadIdx.x, wid = t >> 6, lane = t & 63;
  const int l15 = lane & 15, l4 = lane >> 4;
  const int wr = wid >> 1, wc = wid & 1;

  const f32x4_t zero4 = {0.f, 0.f, 0.f, 0.f};
  f32x4_t acc[4][4];
#pragma unroll
  for (int i = 0; i < 4; ++i)
#pragma unroll
    for (int j = 0; j < 4; ++j) acc[i][j] = zero4;

  const char* As = (const char*)vT  + ((size_t)head * HD + d0) * (NNODES * 2) + (size_t)chunk * 8192;
  const char* Bs = (const char*)knT + ((size_t)head * HD + m0) * (NNODES * 2) + (size_t)chunk * 8192;

  for (int c = 0; c < 64; ++c) {
    const int kb = c * 128;
#pragma unroll
    for (int i = 0; i < 4; ++i) {
      int ow = i * 4096 + wid * 1024;
      int o = ow + lane * 16;
      int r = o >> 7, cb = o & 127;
      gl_lds16(As + (size_t)r * (NNODES * 2) + kb + cb, la + ow);
      gl_lds16(Bs + (size_t)r * (NNODES * 2) + kb + cb, lb + ow);
    }
    __syncthreads();
#pragma unroll
    for (int ks = 0; ks < 2; ++ks) {
      const int cc = ks * 64 + l4 * 16;
      bf16x8_t af[4], bfr[4];
#pragma unroll
      for (int i = 0; i < 4; ++i)
        af[i] = *(const bf16x8_t*)(la + (wr * 64 + i * 16 + l15) * 128 + cc);
#pragma unroll
      for (int j = 0; j < 4; ++j)
        bfr[j] = *(const bf16x8_t*)(lb + (wc * 64 + j * 16 + l15) * 128 + cc);
#pragma unroll
      for (int i = 0; i < 4; ++i)
#pragma unroll
        for (int j = 0; j < 4; ++j)
          acc[i][j] = __builtin_amdgcn_mfma_f32_16x16x32_bf16(af[i], bfr[j], acc[i][j], 0, 0, 0);
    }
    __syncthreads();
  }

#pragma unroll
  for (int i = 0; i < 4; ++i)
#pragma unroll
    for (int jj = 0; jj < 4; ++jj)
#pragma unroll
      for (int j = 0; j < 4; ++j) {
        int d = d0 + wr * 64 + i * 16 + l4 * 4 + j;
        int m = m0 + wc * 64 + jj * 16 + l15;
        atomicAdd(&kvT[((size_t)head * HD + d) * HD + m], acc[i][jj][j]);
      }
}

// ---------------- K3: kvT f32 -> bf16 -------------------------------------------------
__global__ void k3_cvt(const float* __restrict__ kvT, bf16_t* __restrict__ kvTb) {
  int i = blockIdx.x * 256 + threadIdx.x;
  float4 v = *(const float4*)(kvT + (size_t)i * 4);
  bf16x4_t b;
  b[0] = f2bf(v.x); b[1] = f2bf(v.y); b[2] = f2bf(v.z); b[3] = f2bf(v.w);
  *(bf16x4_t*)(kvTb + (size_t)i * 4) = b;
}

// ---------------- K4: out = mean_h (qn@kv + vsum) / (qn.ksum + N) ---------------------
__global__ __launch_bounds__(256) void k4_out(
    const bf16_t* __restrict__ qn, const bf16_t* __restrict__ kvTb,
    const float* __restrict__ ksum, const float* __restrict__ vsum,
    float* __restrict__ out) {
  __shared__ __align__(16) bf16_t la[64 * 72];    // qn tile [64][64+8]
  __shared__ __align__(16) bf16_t lb[256 * 72];   // kv tile [256 d][64 m +8]
  __shared__ float sdn[256];

  const int n0 = blockIdx.x * 64;
  const int t = threadIdx.x, wid = t >> 6, lane = t & 63;
  const int l15 = lane & 15, l4 = lane >> 4;

  const f32x4_t zero4 = {0.f, 0.f, 0.f, 0.f};
  f32x4_t oacc[16];
#pragma unroll
  for (int f = 0; f < 16; ++f) oacc[f] = zero4;

  for (int h = 0; h < NH; ++h) {
    f32x4_t hacc[16];
#pragma unroll
    for (int f = 0; f < 16; ++f) hacc[f] = zero4;
    float dnp = 0.f;

    for (int mc = 0; mc < 4; ++mc) {
      const int m0 = mc * 64;
#pragma unroll
      for (int i = 0; i < 2; ++i) {
        int idx = t + i * 256;
        int r = idx >> 3, c8 = (idx & 7) * 8;
        *(bf16x8_t*)(la + r * 72 + c8) =
            *(const bf16x8_t*)(qn + (size_t)(n0 + r) * HDTOT + h * HD + m0 + c8);
      }
#pragma unroll
      for (int i = 0; i < 8; ++i) {
        int idx = t + i * 256;
        int r = idx >> 3, c8 = (idx & 7) * 8;
        *(bf16x8_t*)(lb + r * 72 + c8) =
            *(const bf16x8_t*)(kvTb + ((size_t)h * HD + r) * HD + m0 + c8);
      }
      __syncthreads();
      {
        int r = t & 63, qd = t >> 6;
        float s = 0.f;
#pragma unroll
        for (int j = 0; j < 16; ++j)
          s += (float)la[r * 72 + qd * 16 + j] * ksum[h * HD + m0 + qd * 16 + j];
        dnp += s;
      }
#pragma unroll
      for (int ks = 0; ks < 2; ++ks) {
        const int kk = ks * 32 + l4 * 8;
        bf16x8_t af = *(const bf16x8_t*)(la + (wid * 16 + l15) * 72 + kk);
#pragma unroll
        for (int f = 0; f < 16; ++f) {
          bf16x8_t bf_ = *(const bf16x8_t*)(lb + (f * 16 + l15) * 72 + kk);
          hacc[f] = __builtin_amdgcn_mfma_f32_16x16x32_bf16(af, bf_, hacc[f], 0, 0, 0);
        }
      }
      __syncthreads();
    }
    sdn[t] = dnp;
    __syncthreads();
    if (t < 64) {
      float dn = sdn[t] + sdn[t + 64] + sdn[t + 128] + sdn[t + 192] + 65536.0f;
      sdn[t] = 1.0f / dn;
    }
    __syncthreads();
    float rdn[4];
#pragma unroll
    for (int j = 0; j < 4; ++j) rdn[j] = sdn[wid * 16 + l4 * 4 + j];
#pragma unroll
    for (int f = 0; f < 16; ++f) {
      float vs = vsum[h * HD + f * 16 + l15];
#pragma unroll
      for (int j = 0; j < 4; ++j) oacc[f][j] += (hacc[f][j] + vs) * rdn[j];
    }
    __syncthreads();
  }
#pragma unroll
  for (int f = 0; f < 16; ++f)
#pragma unroll
    for (int j = 0; j < 4; ++j)
      out[(size_t)(n0 + wid * 16 + l4 * 4 + j) * HD + f * 16 + l15] =
          oacc[f][j] * 0.25f;
}

extern "C" void kernel_launch(void* const* d_in, const int* in_sizes, int n_in,
                              void* d_out, int out_size, void* d_ws, size_t ws_size,
                              hipStream_t stream) {
  const float* x  = (const float*)d_in[0];
  const float* Wq = (const float*)d_in[1];
  const float* bq = (const float*)d_in[2];
  const float* Wk = (const float*)d_in[3];
  const float* bk = (const float*)d_in[4];
  const float* Wv = (const float*)d_in[5];
  const float* bv = (const float*)d_in[6];
  float* out = (float*)d_out;
  char* ws = (char*)d_ws;

  // workspace layout (total ~453 MB)
  bf16_t* qn   = (bf16_t*)(ws);                 // [N][1024]        134,217,728 B
  bf16_t* knT  = (bf16_t*)(ws + 134217728L);    // [4][256][N]      134,217,728 B
  bf16_t* vT   = (bf16_t*)(ws + 268435456L);    // [4][256][N]      134,217,728 B
  bf16_t* Wt   = (bf16_t*)(ws + 402653184L);    // [3][1024][512]     3,145,728 B
  float*  kvT  = (float*) (ws + 405798912L);    // [4][256][256]      1,048,576 B
  bf16_t* kvTb = (bf16_t*)(ws + 406847488L);    // [4][256][256]        524,288 B
  float*  ksum = (float*) (ws + 407371776L);    // [4][256]               4,096 B
  float*  vsum = (float*) (ws + 407375872L);    // [4][256]               4,096 B
  bf16_t* xb   = (bf16_t*)(ws + 407379968L);    // [N][512]          67,108,864 B

  hipMemsetAsync(kvT, 0, 1048576, stream);
  hipMemsetAsync(ksum, 0, 8192, stream);  // ksum + vsum contiguous

  k0_wt  <<<dim3(32, 16, 3), 256, 0, stream>>>(Wq, Wk, Wv, Wt);
  k0b_xb <<<dim3(16384),     256, 0, stream>>>(x, xb);
  k1_qkv <<<dim3(12, 512),   512, 0, stream>>>(xb, Wt, bq, bk, bv, qn, knT, vT, ksum, vsum);
  k2_kv  <<<dim3(4, 4, 16),  256, 0, stream>>>(knT, vT, kvT);
  k3_cvt <<<dim3(256),       256, 0, stream>>>(kvT, kvTb);
  k4_out <<<dim3(1024),      256, 0, stream>>>(qn, kvTb, ksum, vsum, out);
}

// Round 3
// 665.027 us; speedup vs baseline: 1.5575x; 1.2372x over previous
//
#include <hip/hip_runtime.h>

#define NNODES 65536
#define INC    512
#define NH     4
#define HD     256
#define HDTOT  1024

typedef __bf16 bf16_t;
typedef __bf16 bf16x4_t __attribute__((ext_vector_type(4)));
typedef __bf16 bf16x8_t __attribute__((ext_vector_type(8)));
typedef float  f32x4_t  __attribute__((ext_vector_type(4)));

__device__ __forceinline__ bf16_t f2bf(float f) { return (bf16_t)f; }

__device__ __forceinline__ void gl_lds16(const void* g, void* l) {
  __builtin_amdgcn_global_load_lds(
      (const __attribute__((address_space(1))) void*)g,
      (__attribute__((address_space(3))) void*)l, 16, 0, 0);
}

// ---------------- K0a: W [512][1024] f32 -> Wt [mat][1024][512] bf16 (transposed) ----
__global__ void k0_wt(const float* __restrict__ Wq, const float* __restrict__ Wk,
                      const float* __restrict__ Wv, bf16_t* __restrict__ Wt) {
  __shared__ float tile[32][33];
  int mat = blockIdx.z;
  const float* W = (mat == 0) ? Wq : (mat == 1) ? Wk : Wv;
  int n0 = blockIdx.x * 32, k0 = blockIdx.y * 32;
  int t = threadIdx.x, tc = t & 31, tr = t >> 5;
#pragma unroll
  for (int i = 0; i < 4; ++i)
    tile[tr + i * 8][tc] = W[(size_t)(k0 + tr + i * 8) * HDTOT + n0 + tc];
  __syncthreads();
#pragma unroll
  for (int i = 0; i < 4; ++i)
    Wt[((size_t)mat * HDTOT + n0 + tr + i * 8) * INC + k0 + tc] =
        f2bf(tile[tc][tr + i * 8]);
}

// ---------------- K0b: x f32 -> xb bf16 ----------------------------------------------
__global__ void k0b_xb(const float* __restrict__ x, bf16_t* __restrict__ xb) {
  size_t i = ((size_t)blockIdx.x * 256 + threadIdx.x) * 8;
  float4 a = *(const float4*)(x + i);
  float4 b = *(const float4*)(x + i + 4);
  bf16x8_t o;
  o[0] = f2bf(a.x); o[1] = f2bf(a.y); o[2] = f2bf(a.z); o[3] = f2bf(a.w);
  o[4] = f2bf(b.x); o[5] = f2bf(b.y); o[6] = f2bf(b.z); o[7] = f2bf(b.w);
  *(bf16x8_t*)(xb + i) = o;
}

// ---------------- K1: QKV projection + bias + q/k row-L2-normalize ------------------
// grid (12, 512): blockIdx.x = mat*4+head, blockIdx.y = 128-row chunk.
// 512 thr = 8 waves (2M x 4N), wave tile 64x64. BK=32, dbuf LDS, 1 barrier/tile.
// knT2/vT2 layout: [h][blk2][nt 1024][128 r][64 n] bf16 (tile-contiguous for K2).
__global__ __launch_bounds__(512, 4) void k1_qkv(
    const bf16_t* __restrict__ xb, const bf16_t* __restrict__ Wt,
    const float* __restrict__ bq, const float* __restrict__ bk,
    const float* __restrict__ bv,
    bf16_t* __restrict__ qn, bf16_t* __restrict__ knT2, bf16_t* __restrict__ vT2,
    float* __restrict__ ksum, float* __restrict__ vsum) {
  __shared__ __align__(16) char smem[52224];
  // bufA[2]: [128][64B] @ 0, 8192 ; bufB[2]: [256][64B] @ 16384, 32768
  bf16_t* ept  = (bf16_t*)smem;            // epilogue tile [64][264|258]
  float* sred  = (float*)(smem + 49152);   // [128][4]
  float* sredc = (float*)(smem + 51200);   // [256]

  const int gxy = blockIdx.x;
  const int mat = gxy >> 2, head = gxy & 3;
  const int n0 = blockIdx.y * 128;
  const int t = threadIdx.x;
  const int wid = t >> 6, lane = t & 63;
  const int l15 = lane & 15, l4 = lane >> 4;
  const int wr = wid >> 2, wc = wid & 3;

  const f32x4_t zero4 = {0.f, 0.f, 0.f, 0.f};
  f32x4_t acc[4][4];
#pragma unroll
  for (int i = 0; i < 4; ++i)
#pragma unroll
    for (int j = 0; j < 4; ++j) acc[i][j] = zero4;

  const char* Ab = (const char*)(xb + (size_t)n0 * INC);
  const char* Bb = (const char*)(Wt + ((size_t)mat * HDTOT + head * HD) * INC);

  auto stage = [&](int kt, int c) {
    const int kb = kt * 64;
    {
      int o = t * 16, r = o >> 6, cb = o & 63;
      gl_lds16(Ab + (size_t)r * 1024 + kb + (cb ^ ((r & 3) << 4)), smem + c * 8192 + o);
    }
#pragma unroll
    for (int i = 0; i < 2; ++i) {
      int o = i * 8192 + t * 16, r = o >> 6, cb = o & 63;
      gl_lds16(Bb + (size_t)r * 1024 + kb + (cb ^ ((r & 3) << 4)),
               smem + 16384 + c * 16384 + o);
    }
  };

  stage(0, 0);
  __syncthreads();
  int cur = 0;
  for (int kt = 0; kt < 16; ++kt) {
    if (kt < 15) stage(kt + 1, cur ^ 1);
    const char* lA = smem + cur * 8192;
    const char* lB = smem + 16384 + cur * 16384;
    bf16x8_t af[4], bfr[4];
#pragma unroll
    for (int i = 0; i < 4; ++i) {
      int r = wr * 64 + i * 16 + l15;
      af[i] = *(const bf16x8_t*)(lA + r * 64 + ((l4 * 16) ^ ((r & 3) << 4)));
    }
#pragma unroll
    for (int j = 0; j < 4; ++j) {
      int r = wc * 64 + j * 16 + l15;
      bfr[j] = *(const bf16x8_t*)(lB + r * 64 + ((l4 * 16) ^ ((r & 3) << 4)));
    }
    __builtin_amdgcn_s_setprio(1);
#pragma unroll
    for (int i = 0; i < 4; ++i)
#pragma unroll
      for (int j = 0; j < 4; ++j)
        acc[i][j] = __builtin_amdgcn_mfma_f32_16x16x32_bf16(af[i], bfr[j], acc[i][j], 0, 0, 0);
    __builtin_amdgcn_s_setprio(0);
    __syncthreads();
    cur ^= 1;
  }

  // bias: col = wc*64 + jf*16 + l15
  const float* bias = (mat == 0) ? bq : (mat == 1) ? bk : bv;
#pragma unroll
  for (int jf = 0; jf < 4; ++jf) {
    float bb = bias[head * HD + wc * 64 + jf * 16 + l15];
#pragma unroll
    for (int i = 0; i < 4; ++i)
#pragma unroll
      for (int jj = 0; jj < 4; ++jj) acc[i][jf][jj] += bb;
  }

  // L2 row-normalize (q, k). Rows span 4 waves (wc) -> LDS reduce.
  if (mat <= 1) {
    float ss[4][4];
#pragma unroll
    for (int i = 0; i < 4; ++i)
#pragma unroll
      for (int jj = 0; jj < 4; ++jj) {
        float s = 0.f;
#pragma unroll
        for (int jf = 0; jf < 4; ++jf) s += acc[i][jf][jj] * acc[i][jf][jj];
        ss[i][jj] = s;
      }
#pragma unroll
    for (int off = 1; off < 16; off <<= 1)
#pragma unroll
      for (int i = 0; i < 4; ++i)
#pragma unroll
        for (int jj = 0; jj < 4; ++jj) ss[i][jj] += __shfl_xor(ss[i][jj], off, 64);
    if (l15 == 0) {
#pragma unroll
      for (int i = 0; i < 4; ++i)
#pragma unroll
        for (int jj = 0; jj < 4; ++jj)
          sred[(wr * 64 + i * 16 + l4 * 4 + jj) * 4 + wc] = ss[i][jj];
    }
    __syncthreads();
#pragma unroll
    for (int i = 0; i < 4; ++i)
#pragma unroll
      for (int jj = 0; jj < 4; ++jj) {
        int row = wr * 64 + i * 16 + l4 * 4 + jj;
        float s = sred[row * 4] + sred[row * 4 + 1] + sred[row * 4 + 2] + sred[row * 4 + 3];
        float rn = rsqrtf(s);
#pragma unroll
        for (int jf = 0; jf < 4; ++jf) acc[i][jf][jj] *= rn;
      }
  }

  // column sums (ksum from normalized k, vsum from v)
  if (mat >= 1) {
    float cs[4];
#pragma unroll
    for (int jf = 0; jf < 4; ++jf) {
      float s = 0.f;
#pragma unroll
      for (int i = 0; i < 4; ++i)
#pragma unroll
        for (int jj = 0; jj < 4; ++jj) s += acc[i][jf][jj];
      s += __shfl_xor(s, 16, 64);
      s += __shfl_xor(s, 32, 64);
      cs[jf] = s;
    }
    if (t < 256) sredc[t] = 0.f;
    __syncthreads();
    if (l4 == 0) {
#pragma unroll
      for (int jf = 0; jf < 4; ++jf)
        atomicAdd(&sredc[wc * 64 + jf * 16 + l15], cs[jf]);
    }
    __syncthreads();
    float* dstSum = (mat == 1) ? ksum : vsum;
    if (t < 256) atomicAdd(dstSum + head * HD + t, sredc[t]);
  }

  // write-out in two 64-row halves via LDS (coalesced; kn/v tile-chunked transposed)
  const int ldp = (mat == 0) ? 264 : 258;
  for (int ph = 0; ph < 2; ++ph) {
    __syncthreads();
    if (wr == ph) {
#pragma unroll
      for (int i = 0; i < 4; ++i)
#pragma unroll
        for (int jf = 0; jf < 4; ++jf)
#pragma unroll
          for (int jj = 0; jj < 4; ++jj)
            ept[(i * 16 + l4 * 4 + jj) * ldp + wc * 64 + jf * 16 + l15] =
                f2bf(acc[i][jf][jj]);
    }
    __syncthreads();
    const int hn0 = n0 + ph * 64;
    if (mat == 0) {
#pragma unroll
      for (int i = 0; i < 4; ++i) {
        int idx = t + i * 512;
        int r = idx >> 5, c8 = (idx & 31) * 8;
        *(bf16x8_t*)(qn + (size_t)(hn0 + r) * HDTOT + head * HD + c8) =
            *(const bf16x8_t*)(ept + r * 264 + c8);
      }
    } else {
      int m = t & 255, seg = t >> 8;
      bf16_t* dst = (mat == 1) ? knT2 : vT2;
      unsigned int pack[16];
#pragma unroll
      for (int rr = 0; rr < 32; rr += 2) {
        int r = seg * 32 + rr;
        unsigned int a = *(const unsigned short*)(ept + r * 258 + m);
        unsigned int b = *(const unsigned short*)(ept + (r + 1) * 258 + m);
        pack[rr >> 1] = a | (b << 16);
      }
      size_t base = ((((size_t)(head * 2 + (m >> 7)) * 1024 + (hn0 >> 6)) * 128 +
                      (m & 127)) * 64) + seg * 32;
      uint4* dp = (uint4*)(dst + base);
#pragma unroll
      for (int i = 0; i < 4; ++i)
        dp[i] = make_uint4(pack[i * 4], pack[i * 4 + 1], pack[i * 4 + 2], pack[i * 4 + 3]);
    }
  }
}

// ---------------- K2: kv partials = v^T kn over node chunks (contiguous tiles) ------
// grid (4, 4 heads, 32 chunks), block 256 = 4 waves (2x2), tile 128x128, BK=64.
__global__ __launch_bounds__(256, 4) void k2_kv(
    const bf16_t* __restrict__ knT2, const bf16_t* __restrict__ vT2,
    float* __restrict__ kvP) {
  __shared__ __align__(16) char smem[65536];  // bufA[2]@0,16384 ; bufB[2]@32768,49152

  const int gx = blockIdx.x;
  const int head = blockIdx.y, ch = blockIdx.z;
  const int td = gx >> 1, tm = gx & 1;

  const int t = threadIdx.x, wid = t >> 6, lane = t & 63;
  const int l15 = lane & 15, l4 = lane >> 4;
  const int wr = wid >> 1, wc = wid & 1;

  const f32x4_t zero4 = {0.f, 0.f, 0.f, 0.f};
  f32x4_t acc[4][4];
#pragma unroll
  for (int i = 0; i < 4; ++i)
#pragma unroll
    for (int j = 0; j < 4; ++j) acc[i][j] = zero4;

  const char* Abase = (const char*)vT2  + ((size_t)(head * 2 + td) * 1024 + ch * 32) * 16384;
  const char* Bbase = (const char*)knT2 + ((size_t)(head * 2 + tm) * 1024 + ch * 32) * 16384;

  auto stage = [&](int it, int c) {
#pragma unroll
    for (int i = 0; i < 4; ++i) {
      int o = i * 4096 + t * 16, r = o >> 7, cb = o & 127;
      int so = r * 128 + (cb ^ ((r & 7) << 4));
      gl_lds16(Abase + (size_t)it * 16384 + so, smem + c * 16384 + o);
      gl_lds16(Bbase + (size_t)it * 16384 + so, smem + 32768 + c * 16384 + o);
    }
  };

  stage(0, 0);
  __syncthreads();
  int cur = 0;
  for (int it = 0; it < 32; ++it) {
    if (it < 31) stage(it + 1, cur ^ 1);
    const char* lA = smem + cur * 16384;
    const char* lB = smem + 32768 + cur * 16384;
#pragma unroll
    for (int ks = 0; ks < 2; ++ks) {
      bf16x8_t af[4], bfr[4];
#pragma unroll
      for (int i = 0; i < 4; ++i) {
        int r = wr * 64 + i * 16 + l15;
        af[i] = *(const bf16x8_t*)(lA + r * 128 + ((ks * 64 + l4 * 16) ^ ((r & 7) << 4)));
      }
#pragma unroll
      for (int j = 0; j < 4; ++j) {
        int r = wc * 64 + j * 16 + l15;
        bfr[j] = *(const bf16x8_t*)(lB + r * 128 + ((ks * 64 + l4 * 16) ^ ((r & 7) << 4)));
      }
      __builtin_amdgcn_s_setprio(1);
#pragma unroll
      for (int i = 0; i < 4; ++i)
#pragma unroll
        for (int j = 0; j < 4; ++j)
          acc[i][j] = __builtin_amdgcn_mfma_f32_16x16x32_bf16(af[i], bfr[j], acc[i][j], 0, 0, 0);
      __builtin_amdgcn_s_setprio(0);
    }
    __syncthreads();
    cur ^= 1;
  }

  float* dst = kvP + ((size_t)(ch * 16 + head * 4 + gx)) * 16384;
#pragma unroll
  for (int i = 0; i < 4; ++i)
#pragma unroll
    for (int jj = 0; jj < 4; ++jj)
#pragma unroll
      for (int j = 0; j < 4; ++j)
        dst[(wr * 64 + i * 16 + l4 * 4 + j) * 128 + wc * 64 + jj * 16 + l15] =
            acc[i][jj][j];
}

// ---------------- K3: reduce 32 kv partials + convert to bf16 ------------------------
__global__ void k3_red(const float* __restrict__ kvP, bf16_t* __restrict__ kvTb) {
  int tid = blockIdx.x * 256 + threadIdx.x;  // 65536 threads, 4 outputs each
  int base = tid * 4;
  int m = base & 255, d = (base >> 8) & 255, h = base >> 16;
  int gx = ((d >> 7) << 1) | (m >> 7);
  int off = (d & 127) * 128 + (m & 127);
  f32x4_t s = {0.f, 0.f, 0.f, 0.f};
#pragma unroll
  for (int ch = 0; ch < 32; ++ch)
    s += *(const f32x4_t*)(kvP + (((size_t)(ch * 16 + h * 4 + gx)) << 14) + off);
  bf16x4_t b;
  b[0] = f2bf(s[0]); b[1] = f2bf(s[1]); b[2] = f2bf(s[2]); b[3] = f2bf(s[3]);
  *(bf16x4_t*)(kvTb + (size_t)base) = b;
}

// ---------------- K4: out = mean_h (qn@kv + vsum) / (qn.ksum + N) ---------------------
// grid (1024), block 256 = 4 waves, block tile 64 rows x 256 d, wave tile 16x256.
__global__ __launch_bounds__(256, 2) void k4_out(
    const bf16_t* __restrict__ qn, const bf16_t* __restrict__ kvTb,
    const float* __restrict__ ksum, const float* __restrict__ vsum,
    float* __restrict__ out) {
  __shared__ __align__(16) char smem[66560];  // la[64][512B]@0, lb[256][128B]@32768, sdn@65536
  float* sdn = (float*)(smem + 65536);

  const int n0 = blockIdx.x * 64;
  const int t = threadIdx.x, wid = t >> 6, lane = t & 63;
  const int l15 = lane & 15, l4 = lane >> 4;

  const f32x4_t zero4 = {0.f, 0.f, 0.f, 0.f};
  f32x4_t oacc[16];
#pragma unroll
  for (int f = 0; f < 16; ++f) oacc[f] = zero4;

  const char* qb  = (const char*)qn + (size_t)n0 * 2048;
  const char* kvb = (const char*)kvTb;

  for (int h = 0; h < NH; ++h) {
    // stage la: qn rows [64][256 m] for head h (512B contiguous per row)
#pragma unroll
    for (int i = 0; i < 8; ++i) {
      int o = i * 4096 + t * 16, r = o >> 9, cb = o & 511;
      int scb = (cb & 0x180) | ((cb & 0x7F) ^ ((r & 7) << 4));
      gl_lds16(qb + (size_t)r * 2048 + h * 512 + scb, smem + o);
    }
    f32x4_t hacc[16];
#pragma unroll
    for (int f = 0; f < 16; ++f) hacc[f] = zero4;
    float dnp = 0.f;

    for (int mc = 0; mc < 4; ++mc) {
      // stage lb: kvTb[h][256 d][64 m-slice]
#pragma unroll
      for (int i = 0; i < 8; ++i) {
        int o = i * 4096 + t * 16, r = o >> 7, cb = o & 127;
        gl_lds16(kvb + (size_t)h * 131072 + (size_t)r * 512 + mc * 128 +
                     (cb ^ ((r & 7) << 4)),
                 smem + 32768 + o);
      }
      __syncthreads();
      if (mc == 0) {  // denom partial: row r, m-range qd*64..+64 (qd wave-uniform)
        int r = t & 63, qd = t >> 6;
        float s = 0.f;
#pragma unroll
        for (int j = 0; j < 64; ++j) {
          int cb2 = (qd * 64 + j) * 2;
          int a = r * 512 + ((cb2 & 0x180) | ((cb2 & 0x7F) ^ ((r & 7) << 4)));
          s += (float)(*(const bf16_t*)(smem + a)) * ksum[h * HD + qd * 64 + j];
        }
        dnp = s;
      }
#pragma unroll
      for (int ks = 0; ks < 2; ++ks) {
        int ra = wid * 16 + l15;
        bf16x8_t af = *(const bf16x8_t*)(
            smem + ra * 512 + ((mc * 128 + ks * 64 + l4 * 16) ^ ((ra & 7) << 4)));
        __builtin_amdgcn_s_setprio(1);
#pragma unroll
        for (int f = 0; f < 16; ++f) {
          int rb = f * 16 + l15;
          bf16x8_t bfr = *(const bf16x8_t*)(
              smem + 32768 + rb * 128 + ((ks * 64 + l4 * 16) ^ ((rb & 7) << 4)));
          hacc[f] = __builtin_amdgcn_mfma_f32_16x16x32_bf16(af, bfr, hacc[f], 0, 0, 0);
        }
        __builtin_amdgcn_s_setprio(0);
      }
      __syncthreads();
    }
    sdn[t] = dnp;
    __syncthreads();
    if (t < 64)
      sdn[t] = 1.0f / (sdn[t] + sdn[t + 64] + sdn[t + 128] + sdn[t + 192] + 65536.0f);
    __syncthreads();
    float rdn[4];
#pragma unroll
    for (int j = 0; j < 4; ++j) rdn[j] = sdn[wid * 16 + l4 * 4 + j];
#pragma unroll
    for (int f = 0; f < 16; ++f) {
      float vs = vsum[h * HD + f * 16 + l15];
#pragma unroll
      for (int j = 0; j < 4; ++j) oacc[f][j] += (hacc[f][j] + vs) * rdn[j];
    }
    __syncthreads();
  }
#pragma unroll
  for (int f = 0; f < 16; ++f)
#pragma unroll
    for (int j = 0; j < 4; ++j)
      out[(size_t)(n0 + wid * 16 + l4 * 4 + j) * HD + f * 16 + l15] =
          oacc[f][j] * 0.25f;
}

extern "C" void kernel_launch(void* const* d_in, const int* in_sizes, int n_in,
                              void* d_out, int out_size, void* d_ws, size_t ws_size,
                              hipStream_t stream) {
  const float* x  = (const float*)d_in[0];
  const float* Wq = (const float*)d_in[1];
  const float* bq = (const float*)d_in[2];
  const float* Wk = (const float*)d_in[3];
  const float* bk = (const float*)d_in[4];
  const float* Wv = (const float*)d_in[5];
  const float* bv = (const float*)d_in[6];
  float* out = (float*)d_out;
  char* ws = (char*)d_ws;

  // workspace layout (total ~474 MB; kvP aliases xb — k2 runs after k1 consumed xb)
  bf16_t* qn   = (bf16_t*)(ws);                 // [N][1024]        134,217,728 B
  bf16_t* knT2 = (bf16_t*)(ws + 134217728L);    // [4][2][1024][128][64]  134 MB
  bf16_t* vT2  = (bf16_t*)(ws + 268435456L);    // same layout            134 MB
  bf16_t* Wt   = (bf16_t*)(ws + 402653184L);    // [3][1024][512]     3,145,728 B
  bf16_t* kvTb = (bf16_t*)(ws + 406847488L);    // [4][256][256]        524,288 B
  float*  ksum = (float*) (ws + 407371776L);    // [4][256]               4,096 B
  float*  vsum = (float*) (ws + 407375872L);    // [4][256]               4,096 B
  bf16_t* xb   = (bf16_t*)(ws + 407379968L);    // [N][512]          67,108,864 B
  float*  kvP  = (float*) (ws + 407379968L);    // [512][16384] f32  33,554,432 B (alias xb)

  hipMemsetAsync(ksum, 0, 8192, stream);  // ksum + vsum contiguous

  k0_wt  <<<dim3(32, 16, 3), 256, 0, stream>>>(Wq, Wk, Wv, Wt);
  k0b_xb <<<dim3(16384),     256, 0, stream>>>(x, xb);
  k1_qkv <<<dim3(12, 512),   512, 0, stream>>>(xb, Wt, bq, bk, bv, qn, knT2, vT2, ksum, vsum);
  k2_kv  <<<dim3(4, 4, 32),  256, 0, stream>>>(knT2, vT2, kvP);
  k3_red <<<dim3(256),       256, 0, stream>>>(kvP, kvTb);
  k4_out <<<dim3(1024),      256, 0, stream>>>(qn, kvTb, ksum, vsum, out);
}